// Round 4
// baseline (2602.302 us; speedup 1.0000x reference)
//
#include <hip/hip_runtime.h>

#define IN_DIM 256
#define OUT_DIM 64
#define CHB 16384      // histogram bins per chunk (64 KB LDS)
#define NSL 32         // edge slices for histogram

// --- K1: per-slice LDS histogram of col -> partial[slice][node], no global atomics ---
__global__ void __launch_bounds__(512) deg_hist(const int* __restrict__ col,
                                                unsigned* __restrict__ partial,
                                                int E, int N) {
    __shared__ unsigned cnt[CHB];
    int cc = blockIdx.x >> 5;          // bin chunk
    int ss = blockIdx.x & 31;          // edge slice
    for (int j = threadIdx.x; j < CHB; j += 512) cnt[j] = 0;
    __syncthreads();
    int base = cc * CHB;
    int sl = (E + NSL - 1) / NSL;
    int e0 = ss * sl, e1 = min(E, e0 + sl);
    for (int e = e0 + threadIdx.x; e < e1; e += 512) {
        int rel = col[e] - base;
        if ((unsigned)rel < (unsigned)CHB) atomicAdd(&cnt[rel], 1u);
    }
    __syncthreads();
    unsigned* dst = partial + (size_t)ss * N;
    for (int j = threadIdx.x; j < CHB; j += 512)
        if (base + j < N) dst[base + j] = cnt[j];
}

// --- K2: deg = sum of partials; dinv = rsqrt(deg+1); bkt[b] = edges per 128-node bucket ---
__global__ void __launch_bounds__(256) deg_reduce(const unsigned* __restrict__ partial,
                                                  float* __restrict__ dinv,
                                                  int* __restrict__ bkt, int N, int NB) {
    int w = threadIdx.x >> 6, lane = threadIdx.x & 63;
    int b = blockIdx.x * 4 + w;
    if (b >= NB) return;
    int i0 = b * 128 + lane, i1 = i0 + 64;
    unsigned d0 = 0, d1 = 0;
    for (int s = 0; s < NSL; s++) {
        const unsigned* p = partial + (size_t)s * N;
        if (i0 < N) d0 += p[i0];
        if (i1 < N) d1 += p[i1];
    }
    if (i0 < N) dinv[i0] = rsqrtf((float)(d0 + 1));
    if (i1 < N) dinv[i1] = rsqrtf((float)(d1 + 1));
    int t = (int)(d0 + d1);
#pragma unroll
    for (int m = 32; m > 0; m >>= 1) t += __shfl_xor(t, m);
    if (lane == 0) bkt[b] = t;
}

// --- K3: exclusive prefix over buckets -> bstart, cursor ---
__global__ void __launch_bounds__(1024) prefix_kernel(const int* __restrict__ bkt,
                                                      int* __restrict__ bstart,
                                                      int* __restrict__ cursor, int NB) {
    __shared__ int ls[1024];
    int t = threadIdx.x;
    ls[t] = (t < NB) ? bkt[t] : 0;
    __syncthreads();
    for (int off = 1; off < 1024; off <<= 1) {
        int v = (t >= off) ? ls[t - off] : 0;
        __syncthreads();
        ls[t] += v;
        __syncthreads();
    }
    if (t < NB) {
        int excl = ls[t] - bkt[t];
        bstart[t] = excl;
        cursor[t] = excl;
        if (t == NB - 1) bstart[NB] = ls[t];
    }
}

// --- K4: hs = dinv[row] * (x @ W) ---
__global__ void __launch_bounds__(256) gemm_kernel(const float* __restrict__ x,
                                                   const float* __restrict__ W,
                                                   const float* __restrict__ dinv,
                                                   float* __restrict__ hs, int N) {
    __shared__ float Wl[IN_DIM * OUT_DIM];
    int t = threadIdx.x;
    const float4* W4 = (const float4*)W;
    float4* Wl4 = (float4*)Wl;
#pragma unroll
    for (int i = 0; i < 16; i++) Wl4[t + i * 256] = W4[t + i * 256];
    __syncthreads();

    int wave = t >> 6, lane = t & 63;
    int r0 = (blockIdx.x * 4 + wave) * 8;
    if (r0 >= N) return;

    float acc[8];
#pragma unroll
    for (int rr = 0; rr < 8; rr++) acc[rr] = 0.f;

    const float4* x4 = (const float4*)x + (size_t)r0 * (IN_DIM / 4);
#pragma unroll 4
    for (int k4 = 0; k4 < IN_DIM / 4; k4++) {
        float w0 = Wl[(4 * k4 + 0) * OUT_DIM + lane];
        float w1 = Wl[(4 * k4 + 1) * OUT_DIM + lane];
        float w2 = Wl[(4 * k4 + 2) * OUT_DIM + lane];
        float w3 = Wl[(4 * k4 + 3) * OUT_DIM + lane];
#pragma unroll
        for (int rr = 0; rr < 8; rr++) {
            float4 xv = x4[rr * (IN_DIM / 4) + k4];
            acc[rr] = fmaf(xv.x, w0, acc[rr]);
            acc[rr] = fmaf(xv.y, w1, acc[rr]);
            acc[rr] = fmaf(xv.z, w2, acc[rr]);
            acc[rr] = fmaf(xv.w, w3, acc[rr]);
        }
    }
#pragma unroll
    for (int rr = 0; rr < 8; rr++)
        hs[(size_t)(r0 + rr) * OUT_DIM + lane] = acc[rr] * dinv[r0 + rr];
}

// --- K5: scatter edges into bucket lists, packed (row<<7 | col&127) ---
__global__ void scatter_kernel(const int* __restrict__ row, const int* __restrict__ col,
                               int* __restrict__ cursor, unsigned* __restrict__ ebuf, int E) {
    int e = blockIdx.x * blockDim.x + threadIdx.x;
    if (e >= E) return;
    int c = col[e], r = row[e];
    int pos = atomicAdd(&cursor[c >> 7], 1);
    ebuf[pos] = ((unsigned)r << 7) | (unsigned)(c & 127);
}

// --- K6: per-bucket LDS aggregation + fused epilogue ---
__global__ void __launch_bounds__(256) agg_kernel(const unsigned* __restrict__ ebuf,
                                                  const int* __restrict__ bstart,
                                                  const float* __restrict__ hs,
                                                  const float* __restrict__ dinv,
                                                  const float* __restrict__ bias,
                                                  float* __restrict__ out, int N) {
    __shared__ float acc[128 * OUT_DIM];   // 32 KB
    int t = threadIdx.x, w = t >> 6, lane = t & 63;
    int b = blockIdx.x;
    for (int j = t; j < 128 * OUT_DIM; j += 256) acc[j] = 0.f;
    __syncthreads();

    int e0 = bstart[b], e1 = bstart[b + 1];
    int cnt = e1 - e0;
    int chunk = (cnt + 3) >> 2;
    int p0 = e0 + w * chunk;
    int p1 = min(e1, p0 + chunk);
    int p = p0;
    for (; p + 4 <= p1; p += 4) {
        unsigned q0 = ebuf[p], q1 = ebuf[p + 1], q2 = ebuf[p + 2], q3 = ebuf[p + 3];
        float v0 = hs[(size_t)(q0 >> 7) * OUT_DIM + lane];
        float v1 = hs[(size_t)(q1 >> 7) * OUT_DIM + lane];
        float v2 = hs[(size_t)(q2 >> 7) * OUT_DIM + lane];
        float v3 = hs[(size_t)(q3 >> 7) * OUT_DIM + lane];
        atomicAdd(&acc[(q0 & 127) * OUT_DIM + lane], v0);
        atomicAdd(&acc[(q1 & 127) * OUT_DIM + lane], v1);
        atomicAdd(&acc[(q2 & 127) * OUT_DIM + lane], v2);
        atomicAdd(&acc[(q3 & 127) * OUT_DIM + lane], v3);
    }
    for (; p < p1; p++) {
        unsigned q = ebuf[p];
        atomicAdd(&acc[(q & 127) * OUT_DIM + lane], hs[(size_t)(q >> 7) * OUT_DIM + lane]);
    }
    __syncthreads();

    // epilogue: 32 nodes per wave
    for (int k = 0; k < 32; k++) {
        int n = w * 32 + k;
        int c = b * 128 + n;
        if (c >= N) break;
        float dc = dinv[c];
        float tot = fmaf(dc, acc[n * OUT_DIM + lane] + hs[(size_t)c * OUT_DIM + lane],
                         bias[lane]);
        float mn = tot, mx = tot;
#pragma unroll
        for (int m = 32; m > 0; m >>= 1) {
            mn = fminf(mn, __shfl_xor(mn, m));
            mx = fmaxf(mx, __shfl_xor(mx, m));
        }
        float z = (tot - mn) / (mx - mn);
        float sq = z * z;
#pragma unroll
        for (int m = 32; m > 0; m >>= 1) sq += __shfl_xor(sq, m);
        out[(size_t)c * OUT_DIM + lane] = z / fmaxf(sqrtf(sq), 1e-12f);
    }
}

extern "C" void kernel_launch(void* const* d_in, const int* in_sizes, int n_in,
                              void* d_out, int out_size, void* d_ws, size_t ws_size,
                              hipStream_t stream) {
    const float* x = (const float*)d_in[0];
    const int*   ei = (const int*)d_in[1];
    const float* W = (const float*)d_in[2];
    const float* b = (const float*)d_in[3];
    float* out = (float*)d_out;

    int N = in_sizes[0] / IN_DIM;      // 100000
    int E = in_sizes[1] / 2;           // 3200000
    const int* row = ei;               // sources
    const int* col = ei + E;           // targets
    int NB = (N + 127) >> 7;           // 782 buckets

    // workspace layout; partial (32*N u32) and ebuf (E u32) alias (disjoint lifetimes)
    char* wp = (char*)d_ws;
    float* hs = (float*)wp;            wp += (size_t)N * OUT_DIM * 4;
    size_t regA = (size_t)NSL * N * 4; size_t regB = (size_t)E * 4;
    unsigned* partial = (unsigned*)wp;
    unsigned* ebuf    = (unsigned*)wp; wp += (regA > regB ? regA : regB);
    float* dinv  = (float*)wp;         wp += (size_t)N * 4;
    int* bkt     = (int*)wp;           wp += (size_t)NB * 4;
    int* bstart  = (int*)wp;           wp += (size_t)(NB + 1) * 4;
    int* cursor  = (int*)wp;           wp += (size_t)NB * 4;

    int nch = (N + CHB - 1) / CHB;     // 7 bin chunks
    deg_hist<<<nch * NSL, 512, 0, stream>>>(col, partial, E, N);
    deg_reduce<<<(NB + 3) / 4, 256, 0, stream>>>(partial, dinv, bkt, N, NB);
    prefix_kernel<<<1, 1024, 0, stream>>>(bkt, bstart, cursor, NB);
    gemm_kernel<<<(N + 31) / 32, 256, 0, stream>>>(x, W, dinv, hs, N);
    scatter_kernel<<<(E + 255) / 256, 256, 0, stream>>>(row, col, cursor, ebuf, E);
    agg_kernel<<<NB, 256, 0, stream>>>(ebuf, bstart, hs, dinv, b, out, N);
}

// Round 5
// 1115.841 us; speedup vs baseline: 2.3321x; 2.3321x over previous
//
#include <hip/hip_runtime.h>

#define IN_DIM 256
#define OUT_DIM 64
#define CHB 16384      // histogram bins per chunk (64 KB LDS)
#define NSL 32         // edge slices for histogram

// --- K1: per-slice LDS histogram of col -> partial[slice][node], no global atomics ---
__global__ void __launch_bounds__(512) deg_hist(const int* __restrict__ col,
                                                unsigned* __restrict__ partial,
                                                int E, int N) {
    __shared__ unsigned cnt[CHB];
    int cc = blockIdx.x >> 5;          // bin chunk
    int ss = blockIdx.x & 31;          // edge slice
    for (int j = threadIdx.x; j < CHB; j += 512) cnt[j] = 0;
    __syncthreads();
    int base = cc * CHB;
    int sl = (E + NSL - 1) / NSL;
    int e0 = ss * sl, e1 = min(E, e0 + sl);
    for (int e = e0 + threadIdx.x; e < e1; e += 512) {
        int rel = col[e] - base;
        if ((unsigned)rel < (unsigned)CHB) atomicAdd(&cnt[rel], 1u);
    }
    __syncthreads();
    unsigned* dst = partial + (size_t)ss * N;
    for (int j = threadIdx.x; j < CHB; j += 512) {
        int i = base + j;
        if (i < N) dst[i] = cnt[j];
    }
}

// --- K2: deg[i] = sum over slices of partial[s][i] ---
__global__ void deg_reduce(const unsigned* __restrict__ partial,
                           int* __restrict__ deg, int N) {
    int i = blockIdx.x * blockDim.x + threadIdx.x;
    if (i >= N) return;
    unsigned d = 0;
#pragma unroll
    for (int s = 0; s < NSL; s++) d += partial[(size_t)s * N + i];
    deg[i] = (int)d;
}

// --- K3: single-block exclusive scan -> start/cursor; dinv = rsqrt(deg+1) ---
__global__ void __launch_bounds__(1024) scan_kernel(const int* __restrict__ deg,
                                                    int* __restrict__ start,
                                                    int* __restrict__ cursor,
                                                    float* __restrict__ dinv, int N) {
    __shared__ int lsum[1024];
    int t = threadIdx.x;
    int CH = (N + 1023) >> 10;
    int lo = t * CH;
    int hi = lo + CH; if (hi > N) hi = N;
    int s = 0;
    for (int i = lo; i < hi; i++) s += deg[i];
    lsum[t] = s;
    __syncthreads();
    for (int off = 1; off < 1024; off <<= 1) {
        int v = (t >= off) ? lsum[t - off] : 0;
        __syncthreads();
        lsum[t] += v;
        __syncthreads();
    }
    int run = (t == 0) ? 0 : lsum[t - 1];
    for (int i = lo; i < hi; i++) {
        int d = deg[i];
        start[i] = run;
        cursor[i] = run;
        dinv[i] = rsqrtf((float)(d + 1));
        run += d;
    }
    if (t == 1023) start[N] = run;
}

// --- K4: hs = dinv[row] * (x @ W) ---
__global__ void __launch_bounds__(256) gemm_kernel(const float* __restrict__ x,
                                                   const float* __restrict__ W,
                                                   const float* __restrict__ dinv,
                                                   float* __restrict__ hs, int N) {
    __shared__ float Wl[IN_DIM * OUT_DIM];
    int t = threadIdx.x;
    const float4* W4 = (const float4*)W;
    float4* Wl4 = (float4*)Wl;
#pragma unroll
    for (int i = 0; i < 16; i++) Wl4[t + i * 256] = W4[t + i * 256];
    __syncthreads();

    int wave = t >> 6, lane = t & 63;
    int r0 = (blockIdx.x * 4 + wave) * 8;
    if (r0 >= N) return;

    float acc[8];
#pragma unroll
    for (int rr = 0; rr < 8; rr++) acc[rr] = 0.f;

    const float4* x4 = (const float4*)x + (size_t)r0 * (IN_DIM / 4);
#pragma unroll 4
    for (int k4 = 0; k4 < IN_DIM / 4; k4++) {
        float w0 = Wl[(4 * k4 + 0) * OUT_DIM + lane];
        float w1 = Wl[(4 * k4 + 1) * OUT_DIM + lane];
        float w2 = Wl[(4 * k4 + 2) * OUT_DIM + lane];
        float w3 = Wl[(4 * k4 + 3) * OUT_DIM + lane];
#pragma unroll
        for (int rr = 0; rr < 8; rr++) {
            float4 xv = x4[rr * (IN_DIM / 4) + k4];
            acc[rr] = fmaf(xv.x, w0, acc[rr]);
            acc[rr] = fmaf(xv.y, w1, acc[rr]);
            acc[rr] = fmaf(xv.z, w2, acc[rr]);
            acc[rr] = fmaf(xv.w, w3, acc[rr]);
        }
    }
#pragma unroll
    for (int rr = 0; rr < 8; rr++)
        hs[(size_t)(r0 + rr) * OUT_DIM + lane] = acc[rr] * dinv[r0 + rr];
}

// --- K5: fill CSR lists via per-node cursors (contention = avg degree 32) ---
__global__ void fill_kernel(const int* __restrict__ row, const int* __restrict__ col,
                            int* __restrict__ cursor, int* __restrict__ csr, int E) {
    int e = blockIdx.x * blockDim.x + threadIdx.x;
    if (e < E) {
        int pos = atomicAdd(&cursor[col[e]], 1);
        csr[pos] = row[e];
    }
}

// --- K6: pull aggregation (8-way unrolled) + bias + min-max + L2 norm ---
__global__ void __launch_bounds__(256) agg_kernel(const float* __restrict__ hs,
                                                  const int* __restrict__ start,
                                                  const int* __restrict__ csr,
                                                  const float* __restrict__ dinv,
                                                  const float* __restrict__ bias,
                                                  float* __restrict__ out, int N) {
    int t = threadIdx.x;
    int w = t >> 6, lane = t & 63;
    int c = blockIdx.x * 4 + w;
    if (c >= N) return;

    float dc = dinv[c];
    float acc = hs[(size_t)c * OUT_DIM + lane];    // self-loop (hs pre-scaled by dinv)
    int p = start[c], e2 = start[c + 1];

    float a0 = 0.f, a1 = 0.f, a2 = 0.f, a3 = 0.f;
    float a4 = 0.f, a5 = 0.f, a6 = 0.f, a7 = 0.f;
    for (; p + 8 <= e2; p += 8) {
        int r0 = csr[p + 0], r1 = csr[p + 1], r2 = csr[p + 2], r3 = csr[p + 3];
        int r4 = csr[p + 4], r5 = csr[p + 5], r6 = csr[p + 6], r7 = csr[p + 7];
        a0 += hs[(size_t)r0 * OUT_DIM + lane];
        a1 += hs[(size_t)r1 * OUT_DIM + lane];
        a2 += hs[(size_t)r2 * OUT_DIM + lane];
        a3 += hs[(size_t)r3 * OUT_DIM + lane];
        a4 += hs[(size_t)r4 * OUT_DIM + lane];
        a5 += hs[(size_t)r5 * OUT_DIM + lane];
        a6 += hs[(size_t)r6 * OUT_DIM + lane];
        a7 += hs[(size_t)r7 * OUT_DIM + lane];
    }
    for (; p < e2; ++p) a0 += hs[(size_t)csr[p] * OUT_DIM + lane];
    acc += ((a0 + a1) + (a2 + a3)) + ((a4 + a5) + (a6 + a7));

    float tot = fmaf(dc, acc, bias[lane]);

    float mn = tot, mx = tot;
#pragma unroll
    for (int m = 32; m > 0; m >>= 1) {
        mn = fminf(mn, __shfl_xor(mn, m));
        mx = fmaxf(mx, __shfl_xor(mx, m));
    }
    float z = (tot - mn) / (mx - mn);
    float sq = z * z;
#pragma unroll
    for (int m = 32; m > 0; m >>= 1) sq += __shfl_xor(sq, m);
    out[(size_t)c * OUT_DIM + lane] = z / fmaxf(sqrtf(sq), 1e-12f);
}

extern "C" void kernel_launch(void* const* d_in, const int* in_sizes, int n_in,
                              void* d_out, int out_size, void* d_ws, size_t ws_size,
                              hipStream_t stream) {
    const float* x = (const float*)d_in[0];
    const int*   ei = (const int*)d_in[1];
    const float* W = (const float*)d_in[2];
    const float* b = (const float*)d_in[3];
    float* out = (float*)d_out;

    int N = in_sizes[0] / IN_DIM;      // 100000
    int E = in_sizes[1] / 2;           // 3200000
    const int* row = ei;               // sources
    const int* col = ei + E;           // targets

    // workspace: hs 25.6MB | partial 12.8MB (aliased with csr 12.8MB) | small arrays
    char* wp = (char*)d_ws;
    float* hs = (float*)wp;            wp += (size_t)N * OUT_DIM * 4;
    size_t regA = (size_t)NSL * N * 4, regB = (size_t)E * 4;
    unsigned* partial = (unsigned*)wp;   // lifetime: deg_hist..deg_reduce
    int*      csr     = (int*)wp;        // lifetime: fill..agg (after partial dead)
    wp += (regA > regB ? regA : regB);
    int*   deg    = (int*)wp;          wp += (size_t)N * 4;
    int*   start  = (int*)wp;          wp += (size_t)(N + 1) * 4;
    int*   cursor = (int*)wp;          wp += (size_t)N * 4;
    float* dinv   = (float*)wp;        wp += (size_t)N * 4;

    int nch = (N + CHB - 1) / CHB;     // 7 bin chunks
    deg_hist<<<nch * NSL, 512, 0, stream>>>(col, partial, E, N);
    deg_reduce<<<(N + 255) / 256, 256, 0, stream>>>(partial, deg, N);
    scan_kernel<<<1, 1024, 0, stream>>>(deg, start, cursor, dinv, N);
    gemm_kernel<<<(N + 31) / 32, 256, 0, stream>>>(x, W, dinv, hs, N);
    fill_kernel<<<(E + 255) / 256, 256, 0, stream>>>(row, col, cursor, csr, E);
    agg_kernel<<<(N + 3) / 4, 256, 0, stream>>>(hs, start, csr, dinv, b, out, N);
}

// Round 6
// 771.003 us; speedup vs baseline: 3.3752x; 1.4473x over previous
//
#include <hip/hip_runtime.h>

#define IN_DIM 256
#define OUT_DIM 64
#define CHB 16384      // histogram bins per chunk (64 KB LDS)
#define NSL 32         // edge slices

// --- K1: per-slice LDS histogram of col -> partial[slice][node] ---
__global__ void __launch_bounds__(512) deg_hist(const int* __restrict__ col,
                                                unsigned* __restrict__ partial,
                                                int E, int N) {
    __shared__ unsigned cnt[CHB];
    int cc = blockIdx.x >> 5;          // bin chunk
    int ss = blockIdx.x & 31;          // edge slice
    for (int j = threadIdx.x; j < CHB; j += 512) cnt[j] = 0;
    __syncthreads();
    int base = cc * CHB;
    int sl = (E + NSL - 1) / NSL;
    int e0 = ss * sl, e1 = min(E, e0 + sl);
    for (int e = e0 + threadIdx.x; e < e1; e += 512) {
        int rel = col[e] - base;
        if ((unsigned)rel < (unsigned)CHB) atomicAdd(&cnt[rel], 1u);
    }
    __syncthreads();
    unsigned* dst = partial + (size_t)ss * N;
    for (int j = threadIdx.x; j < CHB; j += 512) {
        int i = base + j;
        if (i < N) dst[i] = cnt[j];
    }
}

// --- K2: deg[i] = sum over slices; block sum -> bsum[block] ---
__global__ void __launch_bounds__(256) deg_reduce_bsum(const unsigned* __restrict__ partial,
                                                       int* __restrict__ deg,
                                                       int* __restrict__ bsum, int N) {
    __shared__ int red[256];
    int t = threadIdx.x;
    int i = blockIdx.x * 256 + t;
    unsigned d = 0;
    if (i < N) {
#pragma unroll
        for (int s = 0; s < NSL; s++) d += partial[(size_t)s * N + i];
        deg[i] = (int)d;
    }
    red[t] = (int)d;
    __syncthreads();
    for (int off = 128; off > 0; off >>= 1) {
        if (t < off) red[t] += red[t + off];
        __syncthreads();
    }
    if (t == 0) bsum[blockIdx.x] = red[0];
}

// --- K3: exclusive scan of block sums (nb <= 1024) ---
__global__ void __launch_bounds__(1024) bscan(const int* __restrict__ bsum,
                                              int* __restrict__ boff, int nb) {
    __shared__ int ls[1024];
    int t = threadIdx.x;
    int v = (t < nb) ? bsum[t] : 0;
    ls[t] = v;
    __syncthreads();
    for (int off = 1; off < 1024; off <<= 1) {
        int u = (t >= off) ? ls[t - off] : 0;
        __syncthreads();
        ls[t] += u;
        __syncthreads();
    }
    if (t < nb) boff[t] = ls[t] - v;
}

// --- K4: per-block intra-scan -> start/cursor; dinv = rsqrt(deg+1) ---
__global__ void __launch_bounds__(256) node_scan(const int* __restrict__ deg,
                                                 const int* __restrict__ boff,
                                                 int* __restrict__ start,
                                                 int* __restrict__ cursor,
                                                 float* __restrict__ dinv, int N) {
    __shared__ int ls[256];
    int t = threadIdx.x;
    int i = blockIdx.x * 256 + t;
    int d = (i < N) ? deg[i] : 0;
    ls[t] = d;
    __syncthreads();
    for (int off = 1; off < 256; off <<= 1) {
        int u = (t >= off) ? ls[t - off] : 0;
        __syncthreads();
        ls[t] += u;
        __syncthreads();
    }
    if (i < N) {
        int st = boff[blockIdx.x] + ls[t] - d;
        start[i] = st;
        cursor[i] = st;
        dinv[i] = rsqrtf((float)(d + 1));
        if (i == N - 1) start[N] = st + d;
    }
}

// --- K5: in-place per-slice start positions: partial[s][i] = start[i] + prefix ---
__global__ void slice_pos(unsigned* __restrict__ partial, const int* __restrict__ start, int N) {
    int i = blockIdx.x * blockDim.x + threadIdx.x;
    if (i >= N) return;
    unsigned run = (unsigned)start[i];
#pragma unroll
    for (int s = 0; s < NSL; s++) {
        unsigned c = partial[(size_t)s * N + i];
        partial[(size_t)s * N + i] = run;
        run += c;
    }
}

// --- K6: hs = dinv[row] * (x @ W) ---
__global__ void __launch_bounds__(256) gemm_kernel(const float* __restrict__ x,
                                                   const float* __restrict__ W,
                                                   const float* __restrict__ dinv,
                                                   float* __restrict__ hs, int N) {
    __shared__ float Wl[IN_DIM * OUT_DIM];
    int t = threadIdx.x;
    const float4* W4 = (const float4*)W;
    float4* Wl4 = (float4*)Wl;
#pragma unroll
    for (int i = 0; i < 16; i++) Wl4[t + i * 256] = W4[t + i * 256];
    __syncthreads();

    int wave = t >> 6, lane = t & 63;
    int r0 = (blockIdx.x * 4 + wave) * 8;
    if (r0 >= N) return;

    float acc[8];
#pragma unroll
    for (int rr = 0; rr < 8; rr++) acc[rr] = 0.f;

    const float4* x4 = (const float4*)x + (size_t)r0 * (IN_DIM / 4);
#pragma unroll 4
    for (int k4 = 0; k4 < IN_DIM / 4; k4++) {
        float w0 = Wl[(4 * k4 + 0) * OUT_DIM + lane];
        float w1 = Wl[(4 * k4 + 1) * OUT_DIM + lane];
        float w2 = Wl[(4 * k4 + 2) * OUT_DIM + lane];
        float w3 = Wl[(4 * k4 + 3) * OUT_DIM + lane];
#pragma unroll
        for (int rr = 0; rr < 8; rr++) {
            float4 xv = x4[rr * (IN_DIM / 4) + k4];
            acc[rr] = fmaf(xv.x, w0, acc[rr]);
            acc[rr] = fmaf(xv.y, w1, acc[rr]);
            acc[rr] = fmaf(xv.z, w2, acc[rr]);
            acc[rr] = fmaf(xv.w, w3, acc[rr]);
        }
    }
#pragma unroll
    for (int rr = 0; rr < 8; rr++)
        hs[(size_t)(r0 + rr) * OUT_DIM + lane] = acc[rr] * dinv[r0 + rr];
}

// --- K7a: deterministic chunked fill (no global atomics, localized writes) ---
__global__ void __launch_bounds__(512) fill_det(const int* __restrict__ row,
                                                const int* __restrict__ col,
                                                const unsigned* __restrict__ pstart,
                                                int* __restrict__ csr, int E, int N) {
    __shared__ unsigned cnt[CHB];
    int cc = blockIdx.x >> 5;
    int ss = blockIdx.x & 31;
    int base = cc * CHB;
    for (int j = threadIdx.x; j < CHB; j += 512) {
        int i = base + j;
        cnt[j] = (i < N) ? pstart[(size_t)ss * N + i] : 0u;
    }
    __syncthreads();
    int sl = (E + NSL - 1) / NSL;
    int e0 = ss * sl, e1 = min(E, e0 + sl);
    for (int e = e0 + threadIdx.x; e < e1; e += 512) {
        int rel = col[e] - base;
        if ((unsigned)rel < (unsigned)CHB) {
            unsigned pos = atomicAdd(&cnt[rel], 1u);
            csr[pos] = row[e];
        }
    }
}

// --- K7b fallback: cursor-based fill (proven R5 path) ---
__global__ void fill_cursor(const int* __restrict__ row, const int* __restrict__ col,
                            int* __restrict__ cursor, int* __restrict__ csr, int E) {
    int e = blockIdx.x * blockDim.x + threadIdx.x;
    if (e < E) {
        int pos = atomicAdd(&cursor[col[e]], 1);
        csr[pos] = row[e];
    }
}

// --- K8: pull aggregation (8-way unrolled) + bias + min-max + L2 norm ---
__global__ void __launch_bounds__(256) agg_kernel(const float* __restrict__ hs,
                                                  const int* __restrict__ start,
                                                  const int* __restrict__ csr,
                                                  const float* __restrict__ dinv,
                                                  const float* __restrict__ bias,
                                                  float* __restrict__ out, int N) {
    int t = threadIdx.x;
    int w = t >> 6, lane = t & 63;
    int c = blockIdx.x * 4 + w;
    if (c >= N) return;

    float dc = dinv[c];
    float acc = hs[(size_t)c * OUT_DIM + lane];    // self-loop (hs pre-scaled by dinv)
    int p = start[c], e2 = start[c + 1];

    float a0 = 0.f, a1 = 0.f, a2 = 0.f, a3 = 0.f;
    float a4 = 0.f, a5 = 0.f, a6 = 0.f, a7 = 0.f;
    for (; p + 8 <= e2; p += 8) {
        int r0 = csr[p + 0], r1 = csr[p + 1], r2 = csr[p + 2], r3 = csr[p + 3];
        int r4 = csr[p + 4], r5 = csr[p + 5], r6 = csr[p + 6], r7 = csr[p + 7];
        a0 += hs[(size_t)r0 * OUT_DIM + lane];
        a1 += hs[(size_t)r1 * OUT_DIM + lane];
        a2 += hs[(size_t)r2 * OUT_DIM + lane];
        a3 += hs[(size_t)r3 * OUT_DIM + lane];
        a4 += hs[(size_t)r4 * OUT_DIM + lane];
        a5 += hs[(size_t)r5 * OUT_DIM + lane];
        a6 += hs[(size_t)r6 * OUT_DIM + lane];
        a7 += hs[(size_t)r7 * OUT_DIM + lane];
    }
    for (; p < e2; ++p) a0 += hs[(size_t)csr[p] * OUT_DIM + lane];
    acc += ((a0 + a1) + (a2 + a3)) + ((a4 + a5) + (a6 + a7));

    float tot = fmaf(dc, acc, bias[lane]);

    float mn = tot, mx = tot;
#pragma unroll
    for (int m = 32; m > 0; m >>= 1) {
        mn = fminf(mn, __shfl_xor(mn, m));
        mx = fmaxf(mx, __shfl_xor(mx, m));
    }
    float z = (tot - mn) / (mx - mn);
    float sq = z * z;
#pragma unroll
    for (int m = 32; m > 0; m >>= 1) sq += __shfl_xor(sq, m);
    out[(size_t)c * OUT_DIM + lane] = z / fmaxf(sqrtf(sq), 1e-12f);
}

static inline size_t alup(size_t x) { return (x + 255) & ~(size_t)255; }

extern "C" void kernel_launch(void* const* d_in, const int* in_sizes, int n_in,
                              void* d_out, int out_size, void* d_ws, size_t ws_size,
                              hipStream_t stream) {
    const float* x = (const float*)d_in[0];
    const int*   ei = (const int*)d_in[1];
    const float* W = (const float*)d_in[2];
    const float* b = (const float*)d_in[3];
    float* out = (float*)d_out;

    int N = in_sizes[0] / IN_DIM;      // 100000
    int E = in_sizes[1] / 2;           // 3200000
    const int* row = ei;               // sources
    const int* col = ei + E;           // targets
    int NBLK = (N + 255) / 256;        // 391 scan blocks

    size_t sz_hs   = alup((size_t)N * OUT_DIM * 4);
    size_t sz_part = alup((size_t)NSL * N * 4);
    size_t sz_csr  = alup((size_t)E * 4);
    size_t sz_deg  = alup((size_t)N * 4);
    size_t sz_st   = alup((size_t)(N + 1) * 4);
    size_t sz_cur  = alup((size_t)N * 4);
    size_t sz_dinv = alup((size_t)N * 4);
    size_t sz_bs   = alup(1024 * 4);

    size_t need_det = sz_hs + sz_part + sz_csr + sz_deg + sz_st + sz_cur + sz_dinv + 2 * sz_bs;
    bool det = (ws_size >= need_det);

    char* wp = (char*)d_ws;
    float*    hs      = (float*)wp;    wp += sz_hs;
    unsigned* partial = (unsigned*)wp;
    int*      csr;
    if (det) {                         // partial and csr both live through fill_det
        wp += sz_part;
        csr = (int*)wp;                wp += sz_csr;
    } else {                           // csr aliases partial (R5 proven layout)
        csr = (int*)wp;                wp += (sz_part > sz_csr ? sz_part : sz_csr);
    }
    int*   deg    = (int*)wp;          wp += sz_deg;
    int*   start  = (int*)wp;          wp += sz_st;
    int*   cursor = (int*)wp;          wp += sz_cur;
    float* dinv   = (float*)wp;        wp += sz_dinv;
    int*   bsum   = (int*)wp;          wp += sz_bs;
    int*   boff   = (int*)wp;          wp += sz_bs;

    int nch = (N + CHB - 1) / CHB;     // 7 bin chunks

    deg_hist<<<nch * NSL, 512, 0, stream>>>(col, partial, E, N);
    deg_reduce_bsum<<<NBLK, 256, 0, stream>>>(partial, deg, bsum, N);
    bscan<<<1, 1024, 0, stream>>>(bsum, boff, NBLK);
    node_scan<<<NBLK, 256, 0, stream>>>(deg, boff, start, cursor, dinv, N);
    gemm_kernel<<<(N + 31) / 32, 256, 0, stream>>>(x, W, dinv, hs, N);

    if (det) {
        slice_pos<<<(N + 255) / 256, 256, 0, stream>>>(partial, start, N);
        fill_det<<<nch * NSL, 512, 0, stream>>>(row, col, partial, csr, E, N);
    } else {
        fill_cursor<<<(E + 255) / 256, 256, 0, stream>>>(row, col, cursor, csr, E);
    }

    agg_kernel<<<(N + 3) / 4, 256, 0, stream>>>(hs, start, csr, dinv, b, out, N);
}

// Round 7
// 582.396 us; speedup vs baseline: 4.4683x; 1.3238x over previous
//
#include <hip/hip_runtime.h>

#define IN_DIM 256
#define OUT_DIM 64
#define CHB 16384      // histogram bins per chunk (64 KB LDS)
#define NSL 32         // edge slices

__device__ __forceinline__ unsigned short f2bf(float f) {
    unsigned u = __float_as_uint(f);
    u += 0x7FFF + ((u >> 16) & 1);          // round-to-nearest-even
    return (unsigned short)(u >> 16);
}
__device__ __forceinline__ float bf2f(unsigned short s) {
    return __uint_as_float((unsigned)s << 16);
}

// --- K1: per-slice LDS histogram of col -> partial[slice][node] ---
__global__ void __launch_bounds__(512) deg_hist(const int* __restrict__ col,
                                                unsigned* __restrict__ partial,
                                                int E, int N) {
    __shared__ unsigned cnt[CHB];
    int cc = blockIdx.x >> 5;          // bin chunk
    int ss = blockIdx.x & 31;          // edge slice
    for (int j = threadIdx.x; j < CHB; j += 512) cnt[j] = 0;
    __syncthreads();
    int base = cc * CHB;
    int sl = (E + NSL - 1) / NSL;
    int e0 = ss * sl, e1 = min(E, e0 + sl);
    for (int e = e0 + threadIdx.x; e < e1; e += 512) {
        int rel = col[e] - base;
        if ((unsigned)rel < (unsigned)CHB) atomicAdd(&cnt[rel], 1u);
    }
    __syncthreads();
    unsigned* dst = partial + (size_t)ss * N;
    for (int j = threadIdx.x; j < CHB; j += 512) {
        int i = base + j;
        if (i < N) dst[i] = cnt[j];
    }
}

// --- K2: deg[i] = sum over slices; block sum -> bsum[block] ---
__global__ void __launch_bounds__(256) deg_reduce_bsum(const unsigned* __restrict__ partial,
                                                       int* __restrict__ deg,
                                                       int* __restrict__ bsum, int N) {
    __shared__ int red[256];
    int t = threadIdx.x;
    int i = blockIdx.x * 256 + t;
    unsigned d = 0;
    if (i < N) {
#pragma unroll
        for (int s = 0; s < NSL; s++) d += partial[(size_t)s * N + i];
        deg[i] = (int)d;
    }
    red[t] = (int)d;
    __syncthreads();
    for (int off = 128; off > 0; off >>= 1) {
        if (t < off) red[t] += red[t + off];
        __syncthreads();
    }
    if (t == 0) bsum[blockIdx.x] = red[0];
}

// --- K3: exclusive scan of block sums (nb <= 1024) ---
__global__ void __launch_bounds__(1024) bscan(const int* __restrict__ bsum,
                                              int* __restrict__ boff, int nb) {
    __shared__ int ls[1024];
    int t = threadIdx.x;
    int v = (t < nb) ? bsum[t] : 0;
    ls[t] = v;
    __syncthreads();
    for (int off = 1; off < 1024; off <<= 1) {
        int u = (t >= off) ? ls[t - off] : 0;
        __syncthreads();
        ls[t] += u;
        __syncthreads();
    }
    if (t < nb) boff[t] = ls[t] - v;
}

// --- K4: per-block intra-scan -> start/cursor; dinv = rsqrt(deg+1) ---
__global__ void __launch_bounds__(256) node_scan(const int* __restrict__ deg,
                                                 const int* __restrict__ boff,
                                                 int* __restrict__ start,
                                                 int* __restrict__ cursor,
                                                 float* __restrict__ dinv, int N) {
    __shared__ int ls[256];
    int t = threadIdx.x;
    int i = blockIdx.x * 256 + t;
    int d = (i < N) ? deg[i] : 0;
    ls[t] = d;
    __syncthreads();
    for (int off = 1; off < 256; off <<= 1) {
        int u = (t >= off) ? ls[t - off] : 0;
        __syncthreads();
        ls[t] += u;
        __syncthreads();
    }
    if (i < N) {
        int st = boff[blockIdx.x] + ls[t] - d;
        start[i] = st;
        cursor[i] = st;
        dinv[i] = rsqrtf((float)(d + 1));
        if (i == N - 1) start[N] = st + d;
    }
}

// --- K5: in-place per-slice start positions ---
__global__ void slice_pos(unsigned* __restrict__ partial, const int* __restrict__ start, int N) {
    int i = blockIdx.x * blockDim.x + threadIdx.x;
    if (i >= N) return;
    unsigned run = (unsigned)start[i];
#pragma unroll
    for (int s = 0; s < NSL; s++) {
        unsigned c = partial[(size_t)s * N + i];
        partial[(size_t)s * N + i] = run;
        run += c;
    }
}

// --- K6: blocked GEMM: hsb = bf16( dinv[row] * (x @ W) ). 64x64 tile, K-chunk 64. ---
__global__ void __launch_bounds__(256) gemm_kernel(const float* __restrict__ x,
                                                   const float* __restrict__ W,
                                                   const float* __restrict__ dinv,
                                                   unsigned short* __restrict__ hsb, int N) {
    __shared__ float xs[64 * 68];      // row stride 68: bank-conflict-free
    __shared__ float ws[64 * 64];
    int t = threadIdx.x;
    int br = blockIdx.x * 64;
    int tr = t >> 4, tc = t & 15;

    float4 acc[4];
#pragma unroll
    for (int rr = 0; rr < 4; rr++) acc[rr] = make_float4(0.f, 0.f, 0.f, 0.f);

    const float4* x4 = (const float4*)x;
    const float4* W4 = (const float4*)W;

    for (int kc = 0; kc < IN_DIM; kc += 64) {
#pragma unroll
        for (int i = 0; i < 4; i++) {
            int idx = t + i * 256;
            int r = idx >> 4, c4 = idx & 15;
            int g = br + r;
            float4 v = (g < N) ? x4[(size_t)g * (IN_DIM / 4) + (kc >> 2) + c4]
                               : make_float4(0.f, 0.f, 0.f, 0.f);
            *(float4*)&xs[r * 68 + c4 * 4] = v;
            *(float4*)&ws[r * 64 + c4 * 4] = W4[(size_t)(kc + r) * (OUT_DIM / 4) + c4];
        }
        __syncthreads();
#pragma unroll
        for (int kg = 0; kg < 16; kg++) {
            float4 wv[4];
#pragma unroll
            for (int j = 0; j < 4; j++) wv[j] = *(float4*)&ws[(kg * 4 + j) * 64 + tc * 4];
#pragma unroll
            for (int rr = 0; rr < 4; rr++) {
                float4 xv = *(float4*)&xs[(tr * 4 + rr) * 68 + kg * 4];
                acc[rr].x = fmaf(xv.x, wv[0].x, acc[rr].x);
                acc[rr].y = fmaf(xv.x, wv[0].y, acc[rr].y);
                acc[rr].z = fmaf(xv.x, wv[0].z, acc[rr].z);
                acc[rr].w = fmaf(xv.x, wv[0].w, acc[rr].w);
                acc[rr].x = fmaf(xv.y, wv[1].x, acc[rr].x);
                acc[rr].y = fmaf(xv.y, wv[1].y, acc[rr].y);
                acc[rr].z = fmaf(xv.y, wv[1].z, acc[rr].z);
                acc[rr].w = fmaf(xv.y, wv[1].w, acc[rr].w);
                acc[rr].x = fmaf(xv.z, wv[2].x, acc[rr].x);
                acc[rr].y = fmaf(xv.z, wv[2].y, acc[rr].y);
                acc[rr].z = fmaf(xv.z, wv[2].z, acc[rr].z);
                acc[rr].w = fmaf(xv.z, wv[2].w, acc[rr].w);
                acc[rr].x = fmaf(xv.w, wv[3].x, acc[rr].x);
                acc[rr].y = fmaf(xv.w, wv[3].y, acc[rr].y);
                acc[rr].z = fmaf(xv.w, wv[3].z, acc[rr].z);
                acc[rr].w = fmaf(xv.w, wv[3].w, acc[rr].w);
            }
        }
        __syncthreads();
    }

#pragma unroll
    for (int rr = 0; rr < 4; rr++) {
        int g = br + tr * 4 + rr;
        if (g < N) {
            float s = dinv[g];
            ushort4 sv;
            sv.x = f2bf(acc[rr].x * s);
            sv.y = f2bf(acc[rr].y * s);
            sv.z = f2bf(acc[rr].z * s);
            sv.w = f2bf(acc[rr].w * s);
            *(ushort4*)&hsb[(size_t)g * OUT_DIM + tc * 4] = sv;
        }
    }
}

// --- K7a: deterministic chunked fill ---
__global__ void __launch_bounds__(512) fill_det(const int* __restrict__ row,
                                                const int* __restrict__ col,
                                                const unsigned* __restrict__ pstart,
                                                int* __restrict__ csr, int E, int N) {
    __shared__ unsigned cnt[CHB];
    int cc = blockIdx.x >> 5;
    int ss = blockIdx.x & 31;
    int base = cc * CHB;
    for (int j = threadIdx.x; j < CHB; j += 512) {
        int i = base + j;
        cnt[j] = (i < N) ? pstart[(size_t)ss * N + i] : 0u;
    }
    __syncthreads();
    int sl = (E + NSL - 1) / NSL;
    int e0 = ss * sl, e1 = min(E, e0 + sl);
    for (int e = e0 + threadIdx.x; e < e1; e += 512) {
        int rel = col[e] - base;
        if ((unsigned)rel < (unsigned)CHB) {
            unsigned pos = atomicAdd(&cnt[rel], 1u);
            csr[pos] = row[e];
        }
    }
}

// --- K7b fallback: cursor-based fill ---
__global__ void fill_cursor(const int* __restrict__ row, const int* __restrict__ col,
                            int* __restrict__ cursor, int* __restrict__ csr, int E) {
    int e = blockIdx.x * blockDim.x + threadIdx.x;
    if (e < E) {
        int pos = atomicAdd(&cursor[col[e]], 1);
        csr[pos] = row[e];
    }
}

// --- K8: pull aggregation over bf16 hs + bias + min-max + L2 norm ---
__global__ void __launch_bounds__(256) agg_kernel(const unsigned short* __restrict__ hsb,
                                                  const int* __restrict__ start,
                                                  const int* __restrict__ csr,
                                                  const float* __restrict__ dinv,
                                                  const float* __restrict__ bias,
                                                  float* __restrict__ out, int N) {
    int t = threadIdx.x;
    int w = t >> 6, lane = t & 63;
    int c = blockIdx.x * 4 + w;
    if (c >= N) return;

    float dc = dinv[c];
    float acc = bf2f(hsb[(size_t)c * OUT_DIM + lane]);   // self-loop (pre-scaled)
    int p = start[c], e2 = start[c + 1];

    float a0 = 0.f, a1 = 0.f, a2 = 0.f, a3 = 0.f;
    float a4 = 0.f, a5 = 0.f, a6 = 0.f, a7 = 0.f;
    for (; p + 8 <= e2; p += 8) {
        int r0 = csr[p + 0], r1 = csr[p + 1], r2 = csr[p + 2], r3 = csr[p + 3];
        int r4 = csr[p + 4], r5 = csr[p + 5], r6 = csr[p + 6], r7 = csr[p + 7];
        a0 += bf2f(hsb[(size_t)r0 * OUT_DIM + lane]);
        a1 += bf2f(hsb[(size_t)r1 * OUT_DIM + lane]);
        a2 += bf2f(hsb[(size_t)r2 * OUT_DIM + lane]);
        a3 += bf2f(hsb[(size_t)r3 * OUT_DIM + lane]);
        a4 += bf2f(hsb[(size_t)r4 * OUT_DIM + lane]);
        a5 += bf2f(hsb[(size_t)r5 * OUT_DIM + lane]);
        a6 += bf2f(hsb[(size_t)r6 * OUT_DIM + lane]);
        a7 += bf2f(hsb[(size_t)r7 * OUT_DIM + lane]);
    }
    for (; p < e2; ++p) a0 += bf2f(hsb[(size_t)csr[p] * OUT_DIM + lane]);
    acc += ((a0 + a1) + (a2 + a3)) + ((a4 + a5) + (a6 + a7));

    float tot = fmaf(dc, acc, bias[lane]);

    float mn = tot, mx = tot;
#pragma unroll
    for (int m = 32; m > 0; m >>= 1) {
        mn = fminf(mn, __shfl_xor(mn, m));
        mx = fmaxf(mx, __shfl_xor(mx, m));
    }
    float z = (tot - mn) / (mx - mn);
    float sq = z * z;
#pragma unroll
    for (int m = 32; m > 0; m >>= 1) sq += __shfl_xor(sq, m);
    out[(size_t)c * OUT_DIM + lane] = z / fmaxf(sqrtf(sq), 1e-12f);
}

static inline size_t alup(size_t x) { return (x + 255) & ~(size_t)255; }

extern "C" void kernel_launch(void* const* d_in, const int* in_sizes, int n_in,
                              void* d_out, int out_size, void* d_ws, size_t ws_size,
                              hipStream_t stream) {
    const float* x = (const float*)d_in[0];
    const int*   ei = (const int*)d_in[1];
    const float* W = (const float*)d_in[2];
    const float* b = (const float*)d_in[3];
    float* out = (float*)d_out;

    int N = in_sizes[0] / IN_DIM;      // 100000
    int E = in_sizes[1] / 2;           // 3200000
    const int* row = ei;               // sources
    const int* col = ei + E;           // targets
    int NBLK = (N + 255) / 256;        // scan blocks

    size_t sz_hs   = alup((size_t)N * OUT_DIM * 2);      // bf16 now
    size_t sz_part = alup((size_t)NSL * N * 4);
    size_t sz_csr  = alup((size_t)E * 4);
    size_t sz_deg  = alup((size_t)N * 4);
    size_t sz_st   = alup((size_t)(N + 1) * 4);
    size_t sz_cur  = alup((size_t)N * 4);
    size_t sz_dinv = alup((size_t)N * 4);
    size_t sz_bs   = alup(1024 * 4);

    size_t need_det = sz_hs + sz_part + sz_csr + sz_deg + sz_st + sz_cur + sz_dinv + 2 * sz_bs;
    bool det = (ws_size >= need_det);

    char* wp = (char*)d_ws;
    unsigned short* hsb = (unsigned short*)wp;  wp += sz_hs;
    unsigned* partial = (unsigned*)wp;
    int*      csr;
    if (det) {
        wp += sz_part;
        csr = (int*)wp;                wp += sz_csr;
    } else {
        csr = (int*)wp;                wp += (sz_part > sz_csr ? sz_part : sz_csr);
    }
    int*   deg    = (int*)wp;          wp += sz_deg;
    int*   start  = (int*)wp;          wp += sz_st;
    int*   cursor = (int*)wp;          wp += sz_cur;
    float* dinv   = (float*)wp;        wp += sz_dinv;
    int*   bsum   = (int*)wp;          wp += sz_bs;
    int*   boff   = (int*)wp;          wp += sz_bs;

    int nch = (N + CHB - 1) / CHB;     // 7 bin chunks

    deg_hist<<<nch * NSL, 512, 0, stream>>>(col, partial, E, N);
    deg_reduce_bsum<<<NBLK, 256, 0, stream>>>(partial, deg, bsum, N);
    bscan<<<1, 1024, 0, stream>>>(bsum, boff, NBLK);
    node_scan<<<NBLK, 256, 0, stream>>>(deg, boff, start, cursor, dinv, N);
    gemm_kernel<<<(N + 63) / 64, 256, 0, stream>>>(x, W, dinv, hsb, N);

    if (det) {
        slice_pos<<<(N + 255) / 256, 256, 0, stream>>>(partial, start, N);
        fill_det<<<nch * NSL, 512, 0, stream>>>(row, col, partial, csr, E, N);
    } else {
        fill_cursor<<<(E + 255) / 256, 256, 0, stream>>>(row, col, cursor, csr, E);
    }

    agg_kernel<<<(N + 3) / 4, 256, 0, stream>>>(hsb, start, csr, dinv, b, out, N);
}